// Round 1
// baseline (643.551 us; speedup 1.0000x reference)
//
#include <hip/hip_runtime.h>
#include <hip/hip_bf16.h>
#include <math.h>

#define LOG2PI_F 1.8378770664093453f

typedef __bf16 bf16_t;
typedef bf16_t bf16x8 __attribute__((ext_vector_type(8)));
typedef bf16_t bf16x4 __attribute__((ext_vector_type(4)));
typedef float f32x4 __attribute__((ext_vector_type(4)));

#define M_DIM 16384
#define K_DIM 2048
#define N_DIM 2048
#define BM 128
#define BN 128
#define BK 64
#define NB_N (N_DIM / BN) /* 16 */
#define NB_M (M_DIM / BM) /* 128 */

// ---------------------------------------------------------------------------
// Build Lt[j][i] = L[i][j] in bf16:
//   L[i][j] = Woff[i][j] if i>j ; exp(Wld[i]) if i==j ; 0 if i<j.
// Also emit per-block partial sums of (strict-lower Woff)^2 for trace_cov.
// 64x64 LDS tile transpose; deterministic (no atomics).
// ---------------------------------------------------------------------------
__global__ __launch_bounds__(256) void build_Lt(const float* __restrict__ Woff,
                                                const float* __restrict__ Wld,
                                                bf16_t* __restrict__ Lt,
                                                float* __restrict__ misc_arr) {
    __shared__ float tile[64][65];
    __shared__ float red[4];
    const int jt = blockIdx.x * 64;  // col of L == row of Lt
    const int it = blockIdx.y * 64;  // row of L == col of Lt
    const int tid = threadIdx.x;
    float ss = 0.f;

    if (it + 63 >= jt) {  // tile touches diag or lower triangle -> need Woff
        for (int e = tid; e < 4096; e += 256) {
            int r = e >> 6, c = e & 63;
            tile[r][c] = Woff[(size_t)(it + r) * K_DIM + (jt + c)];
        }
    }
    __syncthreads();

    for (int e = tid; e < 4096; e += 256) {
        int jr = e >> 6, ic = e & 63;  // output row offset (j), col offset (i)
        int i = it + ic, j = jt + jr;
        float v = 0.f;
        if (i > j) {
            v = tile[ic][jr];
            ss += v * v;
        } else if (i == j) {
            v = expf(Wld[i]);
        }
        Lt[(size_t)j * K_DIM + i] = (bf16_t)v;
    }

    // block-reduce ss -> misc_arr[block]
    #pragma unroll
    for (int off = 32; off; off >>= 1) ss += __shfl_down(ss, off);
    if ((tid & 63) == 0) red[tid >> 6] = ss;
    __syncthreads();
    if (tid == 0)
        misc_arr[blockIdx.y * 32 + blockIdx.x] = red[0] + red[1] + red[2] + red[3];
}

// ---------------------------------------------------------------------------
// Cast x -> bf16 and fuse the pred_mean GEMV u[b] = dot(x[b], W_mean).
// One block per row.
// ---------------------------------------------------------------------------
__global__ __launch_bounds__(256) void prep_x(const float* __restrict__ X,
                                              const float* __restrict__ Wm,
                                              bf16_t* __restrict__ Xb,
                                              float* __restrict__ U) {
    const int b = blockIdx.x;
    const int tid = threadIdx.x;
    const float* xr = X + (size_t)b * K_DIM;
    bf16_t* xo = Xb + (size_t)b * K_DIM;
    __shared__ float red[4];
    float dot = 0.f;
    #pragma unroll
    for (int h = 0; h < 2; ++h) {
        int base = h * 1024 + tid * 4;
        float4 v = *(const float4*)(xr + base);
        float4 w = *(const float4*)(Wm + base);
        dot += v.x * w.x + v.y * w.y + v.z * w.z + v.w * w.w;
        bf16x4 p = {(bf16_t)v.x, (bf16_t)v.y, (bf16_t)v.z, (bf16_t)v.w};
        *(bf16x4*)(xo + base) = p;
    }
    #pragma unroll
    for (int off = 32; off; off >>= 1) dot += __shfl_down(dot, off);
    if ((tid & 63) == 0) red[tid >> 6] = dot;
    __syncthreads();
    if (tid == 0) U[b] = red[0] + red[1] + red[2] + red[3];
}

// ---------------------------------------------------------------------------
// quad_gemm: per row b, partial over col block nb of sum_j (x[b] @ L)[j]^2.
// 128x128 tile, BK=64, 4 waves each owning 64x64 (4x4 frags of 16x16x32 bf16).
// Triangular skip: col block [bcol,bcol+128) only needs k >= bcol.
// LDS XOR-swizzled (T2) consistently on write and read (reg-staged).
// ---------------------------------------------------------------------------
__global__ __launch_bounds__(256) void quad_gemm(const bf16_t* __restrict__ Xb,
                                                 const bf16_t* __restrict__ Lt,
                                                 float* __restrict__ qpart) {
    __shared__ bf16_t As[BM * BK];   // 16 KB, logical [128 rows][64 k]
    __shared__ bf16_t Bs[BN * BK];   // 16 KB, logical [128 cols][64 k]  (Lt rows)
    __shared__ float qbuf[2][BM];

    const int nb = blockIdx.x, mb = blockIdx.y;
    const int tid = threadIdx.x;
    const int lane = tid & 63;
    const int wid = tid >> 6;
    const int wr = wid >> 1, wc = wid & 1;
    const int g = lane >> 4, r16 = lane & 15;
    const int brow = mb * BM, bcol = nb * BN;

    f32x4 acc[4][4];
    const f32x4 zero = {0.f, 0.f, 0.f, 0.f};
    #pragma unroll
    for (int m = 0; m < 4; ++m)
        #pragma unroll
        for (int n = 0; n < 4; ++n) acc[m][n] = zero;

    for (int k0 = bcol; k0 < K_DIM; k0 += BK) {
        // ---- stage global -> regs (16B/chunk, 4 chunks each for A and B)
        uint4 av[4], bv[4];
        #pragma unroll
        for (int i = 0; i < 4; ++i) {
            int c = tid + i * 256;      // chunk id 0..1023
            int row = c >> 3, cc = c & 7;
            av[i] = *(const uint4*)(Xb + (size_t)(brow + row) * K_DIM + k0 + cc * 8);
            bv[i] = *(const uint4*)(Lt + (size_t)(bcol + row) * K_DIM + k0 + cc * 8);
        }
        __syncthreads();  // previous iter's LDS reads done
        #pragma unroll
        for (int i = 0; i < 4; ++i) {
            int c = tid + i * 256;
            int row = c >> 3;
            int swz = (c * 16) ^ ((row & 7) << 4);  // byte offset, XOR-swizzled
            *(uint4*)((char*)As + swz) = av[i];
            *(uint4*)((char*)Bs + swz) = bv[i];
        }
        __syncthreads();

        // ---- compute: 2 k-steps of 32
        #pragma unroll
        for (int ks = 0; ks < 2; ++ks) {
            bf16x8 a[4], b[4];
            #pragma unroll
            for (int m = 0; m < 4; ++m) {
                int row = wr * 64 + m * 16 + r16;
                int byteoff = ((row * BK + ks * 32 + g * 8) * 2) ^ ((row & 7) << 4);
                a[m] = *(const bf16x8*)((const char*)As + byteoff);
            }
            #pragma unroll
            for (int n = 0; n < 4; ++n) {
                int row = wc * 64 + n * 16 + r16;
                int byteoff = ((row * BK + ks * 32 + g * 8) * 2) ^ ((row & 7) << 4);
                b[n] = *(const bf16x8*)((const char*)Bs + byteoff);
            }
            #pragma unroll
            for (int m = 0; m < 4; ++m)
                #pragma unroll
                for (int n = 0; n < 4; ++n)
                    acc[m][n] = __builtin_amdgcn_mfma_f32_16x16x32_bf16(a[m], b[n], acc[m][n], 0, 0, 0);
        }
    }

    // ---- epilogue: per-row sum of squares over this block's 128 cols
    // C/D layout (HW-verified): col = lane&15, row = (lane>>4)*4 + reg
    #pragma unroll
    for (int m = 0; m < 4; ++m) {
        #pragma unroll
        for (int r = 0; r < 4; ++r) {
            float s = 0.f;
            #pragma unroll
            for (int n = 0; n < 4; ++n) {
                float t = acc[m][n][r];
                s += t * t;
            }
            #pragma unroll
            for (int off = 1; off < 16; off <<= 1) s += __shfl_xor(s, off);
            if (r16 == 0) qbuf[wc][wr * 64 + m * 16 + g * 4 + r] = s;
        }
    }
    __syncthreads();
    if (tid < BM)
        qpart[(size_t)nb * M_DIM + brow + tid] = qbuf[0][tid] + qbuf[1][tid];
}

// ---------------------------------------------------------------------------
// finalize: weighted ELBO sum over rows + KL/wishart scalar terms. One block.
// ---------------------------------------------------------------------------
__global__ __launch_bounds__(256) void finalize(const float* __restrict__ Y,
                                                const float* __restrict__ Cnt,
                                                const float* __restrict__ nld_p,
                                                const float* __restrict__ Wm,
                                                const float* __restrict__ Wld,
                                                const float* __restrict__ U,
                                                const float* __restrict__ qpart,
                                                const float* __restrict__ misc_arr,
                                                float* __restrict__ out) {
    const int tid = threadIdx.x;
    const float nld = nld_p[0];
    const float inv_sig = expf(-nld);
    const float nprec = inv_sig * inv_sig;

    double s1 = 0.0, s2 = 0.0;
    for (int b = tid; b < M_DIM; b += 256) {
        float c = Cnt[b];
        float q = 0.f;
        #pragma unroll
        for (int nb = 0; nb < NB_N; ++nb) q += qpart[(size_t)nb * M_DIM + b];
        float d = (Y[b] - U[b]) * inv_sig;
        float pl = -0.5f * d * d - nld - 0.5f * LOG2PI_F;
        float tt = 0.5f * q * c * c * nprec;
        s1 += (double)c;
        s2 += (double)((pl - tt) * c);
    }

    double wm2 = 0.0, tcd = 0.0, wls = 0.0, offs = 0.0;
    for (int i = tid; i < K_DIM; i += 256) {
        float w = Wm[i];
        wm2 += (double)w * (double)w;
        float ld = Wld[i];
        tcd += exp(2.0 * (double)ld);
        wls += (double)ld;
    }
    for (int i = tid; i < 1024; i += 256) offs += (double)misc_arr[i];

    __shared__ double red[6][4];
    double vals[6] = {s1, s2, wm2, tcd, wls, offs};
    #pragma unroll
    for (int s = 0; s < 6; ++s) {
        double v = vals[s];
        #pragma unroll
        for (int off = 32; off; off >>= 1) v += __shfl_down(v, off);
        if ((tid & 63) == 0) red[s][tid >> 6] = v;
    }
    __syncthreads();
    if (tid == 0) {
        double S1 = red[0][0] + red[0][1] + red[0][2] + red[0][3];
        double S2 = red[1][0] + red[1][1] + red[1][2] + red[1][3];
        double MSE = red[2][0] + red[2][1] + red[2][2] + red[2][3];
        double TCD = red[3][0] + red[3][1] + red[3][2] + red[3][3];
        double WLS = red[4][0] + red[4][1] + red[4][2] + red[4][3];
        double OFFS = red[5][0] + red[5][1] + red[5][2] + red[5][3];

        double trace_cov = OFFS + TCD;                     // sum(L*L)
        double kl = 0.5 * (MSE + trace_cov - 2.0 * WLS);   // prior_scale=1 -> log term 0
        double wish = 1.5 * (-2.0 * (double)nld) - 0.005 * (double)nprec;
        double elbo = S2 / S1 + 1e-4 * (wish - kl);
        out[0] = (float)(-elbo);
    }
}

// ---------------------------------------------------------------------------
extern "C" void kernel_launch(void* const* d_in, const int* in_sizes, int n_in,
                              void* d_out, int out_size, void* d_ws, size_t ws_size,
                              hipStream_t stream) {
    const float* x    = (const float*)d_in[0];
    const float* y    = (const float*)d_in[1];
    const float* cnt  = (const float*)d_in[2];
    // d_in[3] = noise_mean (unused by the reference math)
    const float* nld  = (const float*)d_in[4];
    const float* Wm   = (const float*)d_in[5];
    const float* Wld  = (const float*)d_in[6];
    const float* Woff = (const float*)d_in[7];

    char* ws = (char*)d_ws;
    bf16_t* Xb     = (bf16_t*)(ws);                 // 16384*2048*2 = 67108864
    bf16_t* Lt     = (bf16_t*)(ws + 67108864);      // 2048*2048*2  =  8388608
    float*  U      = (float*)(ws + 75497472);       // 16384*4      =    65536
    float*  qpart  = (float*)(ws + 75563008);       // 16*16384*4   =  1048576
    float*  misc   = (float*)(ws + 76611584);       // 1024*4       =     4096
    // total 76,615,680 bytes

    build_Lt<<<dim3(32, 32), 256, 0, stream>>>(Woff, Wld, Lt, misc);
    prep_x<<<dim3(M_DIM), 256, 0, stream>>>(x, Wm, Xb, U);
    quad_gemm<<<dim3(NB_N, NB_M), 256, 0, stream>>>(Xb, Lt, qpart);
    finalize<<<1, 256, 0, stream>>>(y, cnt, nld, Wm, Wld, U, qpart, misc, (float*)d_out);
}

// Round 2
// 159.675 us; speedup vs baseline: 4.0304x; 4.0304x over previous
//
#include <hip/hip_runtime.h>
#include <hip/hip_bf16.h>
#include <math.h>

#define LOG2PI_F 1.8378770664093453f

typedef __bf16 bf16_t;
typedef bf16_t bf16x8 __attribute__((ext_vector_type(8)));
typedef bf16_t bf16x4 __attribute__((ext_vector_type(4)));
typedef float f32x4 __attribute__((ext_vector_type(4)));

#define M_DIM 16384
#define K_DIM 2048
#define N_DIM 2048
#define BM 128
#define BN 128
#define BK 64
#define NB_N (N_DIM / BN) /* 16 */
#define NB_M (M_DIM / BM) /* 128 */

// async global->LDS, 16B per lane. LDS dest is wave-uniform base + lane*16.
__device__ __forceinline__ void gload16(const void* g, void* l) {
    __builtin_amdgcn_global_load_lds(
        (__attribute__((address_space(1))) void*)g,
        (__attribute__((address_space(3))) void*)l, 16, 0, 0);
}

// ---------------------------------------------------------------------------
// Build Lt[j][i] = L[i][j] in bf16:
//   L[i][j] = Woff[i][j] if i>j ; exp(Wld[i]) if i==j ; 0 if i<j.
// Also emit per-block partial sums of (strict-lower Woff)^2 for trace_cov.
// ---------------------------------------------------------------------------
__global__ __launch_bounds__(256) void build_Lt(const float* __restrict__ Woff,
                                                const float* __restrict__ Wld,
                                                bf16_t* __restrict__ Lt,
                                                float* __restrict__ misc_arr) {
    __shared__ float tile[64][65];
    __shared__ float red[4];
    const int jt = blockIdx.x * 64;  // col of L == row of Lt
    const int it = blockIdx.y * 64;  // row of L == col of Lt
    const int tid = threadIdx.x;
    float ss = 0.f;

    if (it + 63 >= jt) {  // tile touches diag or lower triangle -> need Woff
        for (int e = tid; e < 4096; e += 256) {
            int r = e >> 6, c = e & 63;
            tile[r][c] = Woff[(size_t)(it + r) * K_DIM + (jt + c)];
        }
    }
    __syncthreads();

    for (int e = tid; e < 4096; e += 256) {
        int jr = e >> 6, ic = e & 63;  // output row offset (j), col offset (i)
        int i = it + ic, j = jt + jr;
        float v = 0.f;
        if (i > j) {
            v = tile[ic][jr];
            ss += v * v;
        } else if (i == j) {
            v = expf(Wld[i]);
        }
        Lt[(size_t)j * K_DIM + i] = (bf16_t)v;
    }

    #pragma unroll
    for (int off = 32; off; off >>= 1) ss += __shfl_down(ss, off);
    if ((tid & 63) == 0) red[tid >> 6] = ss;
    __syncthreads();
    if (tid == 0)
        misc_arr[blockIdx.y * 32 + blockIdx.x] = red[0] + red[1] + red[2] + red[3];
}

// ---------------------------------------------------------------------------
// Cast x -> bf16 and fuse the pred_mean GEMV u[b] = dot(x[b], W_mean).
// ---------------------------------------------------------------------------
__global__ __launch_bounds__(256) void prep_x(const float* __restrict__ X,
                                              const float* __restrict__ Wm,
                                              bf16_t* __restrict__ Xb,
                                              float* __restrict__ U) {
    const int b = blockIdx.x;
    const int tid = threadIdx.x;
    const float* xr = X + (size_t)b * K_DIM;
    bf16_t* xo = Xb + (size_t)b * K_DIM;
    __shared__ float red[4];
    float dot = 0.f;
    #pragma unroll
    for (int h = 0; h < 2; ++h) {
        int base = h * 1024 + tid * 4;
        float4 v = *(const float4*)(xr + base);
        float4 w = *(const float4*)(Wm + base);
        dot += v.x * w.x + v.y * w.y + v.z * w.z + v.w * w.w;
        bf16x4 p = {(bf16_t)v.x, (bf16_t)v.y, (bf16_t)v.z, (bf16_t)v.w};
        *(bf16x4*)(xo + base) = p;
    }
    #pragma unroll
    for (int off = 32; off; off >>= 1) dot += __shfl_down(dot, off);
    if ((tid & 63) == 0) red[tid >> 6] = dot;
    __syncthreads();
    if (tid == 0) U[b] = red[0] + red[1] + red[2] + red[3];
}

// ---------------------------------------------------------------------------
// quad_gemm (m97 structure): global_load_lds staging, linear LDS dest,
// pre-swizzled global source, swizzled ds_read_b128. 128x128 tile, BK=64,
// 4 waves x (64x64 own tile). Triangular skip: k >= bcol only.
// qpart layout: [b][NB_N] row-major.
// ---------------------------------------------------------------------------
__global__ __launch_bounds__(256) void quad_gemm(const bf16_t* __restrict__ Xb,
                                                 const bf16_t* __restrict__ Lt,
                                                 float* __restrict__ qpart) {
    __shared__ bf16_t As[BM * BK];   // 16 KB, linear [row][64k], source-swizzled
    __shared__ bf16_t Bs[BN * BK];   // 16 KB
    __shared__ float qbuf[2][BM];

    const int mb = blockIdx.x, nb = blockIdx.y;
    const int tid = threadIdx.x;
    const int lane = tid & 63;
    const int wid = tid >> 6;
    const int wr = wid >> 1, wc = wid & 1;
    const int g = lane >> 4, r16 = lane & 15;
    const int brow = mb * BM, bcol = nb * BN;

    // ---- staging source pointers (per-lane, pre-swizzled chunk col)
    // issue (wid,j) covers rows wid*32 + j*8 + (lane>>3); chunk col = lane&7.
    // stored chunk c_phys holds global chunk c_phys ^ (row&7); row&7 == lane>>3.
    const int srow = lane >> 3;                // 0..7
    const int scol = (lane & 7) ^ srow;        // swizzled source chunk
    const bf16_t* pA[4];
    const bf16_t* pB[4];
    #pragma unroll
    for (int j = 0; j < 4; ++j) {
        int row = wid * 32 + j * 8 + srow;
        pA[j] = Xb + (size_t)(brow + row) * K_DIM + bcol + scol * 8;
        pB[j] = Lt + (size_t)(bcol + row) * K_DIM + bcol + scol * 8;
    }

    f32x4 acc[4][4];
    const f32x4 zero = {0.f, 0.f, 0.f, 0.f};
    #pragma unroll
    for (int m = 0; m < 4; ++m)
        #pragma unroll
        for (int n = 0; n < 4; ++n) acc[m][n] = zero;

    for (int k0 = bcol; k0 < K_DIM; k0 += BK) {
        __syncthreads();  // previous iter's ds_reads done before overwrite
        #pragma unroll
        for (int j = 0; j < 4; ++j) {
            gload16(pA[j], (char*)As + (wid * 4 + j) * 1024);
            gload16(pB[j], (char*)Bs + (wid * 4 + j) * 1024);
            pA[j] += BK;
            pB[j] += BK;
        }
        __syncthreads();  // compiler drains vmcnt(0) before barrier

        #pragma unroll
        for (int ks = 0; ks < 2; ++ks) {
            bf16x8 a[4], b[4];
            #pragma unroll
            for (int m = 0; m < 4; ++m) {
                int row = wr * 64 + m * 16 + r16;
                int byteoff = ((row * BK + ks * 32 + g * 8) * 2) ^ ((row & 7) << 4);
                a[m] = *(const bf16x8*)((const char*)As + byteoff);
            }
            #pragma unroll
            for (int n = 0; n < 4; ++n) {
                int row = wc * 64 + n * 16 + r16;
                int byteoff = ((row * BK + ks * 32 + g * 8) * 2) ^ ((row & 7) << 4);
                b[n] = *(const bf16x8*)((const char*)Bs + byteoff);
            }
            #pragma unroll
            for (int m = 0; m < 4; ++m)
                #pragma unroll
                for (int n = 0; n < 4; ++n)
                    acc[m][n] = __builtin_amdgcn_mfma_f32_16x16x32_bf16(a[m], b[n], acc[m][n], 0, 0, 0);
        }
    }

    // ---- epilogue: per-row sum of squares over this block's 128 cols
    // C/D layout: col = lane&15, row = (lane>>4)*4 + reg
    #pragma unroll
    for (int m = 0; m < 4; ++m) {
        #pragma unroll
        for (int r = 0; r < 4; ++r) {
            float s = 0.f;
            #pragma unroll
            for (int n = 0; n < 4; ++n) {
                float t = acc[m][n][r];
                s += t * t;
            }
            #pragma unroll
            for (int off = 1; off < 16; off <<= 1) s += __shfl_xor(s, off);
            if (r16 == 0) qbuf[wc][wr * 64 + m * 16 + g * 4 + r] = s;
        }
    }
    __syncthreads();
    if (tid < BM)
        qpart[(size_t)(brow + tid) * NB_N + nb] = qbuf[0][tid] + qbuf[1][tid];
}

// ---------------------------------------------------------------------------
// finalize: weighted ELBO sum over rows + KL/wishart scalar terms. One block.
// ---------------------------------------------------------------------------
__global__ __launch_bounds__(256) void finalize(const float* __restrict__ Y,
                                                const float* __restrict__ Cnt,
                                                const float* __restrict__ nld_p,
                                                const float* __restrict__ Wm,
                                                const float* __restrict__ Wld,
                                                const float* __restrict__ U,
                                                const float* __restrict__ qpart,
                                                const float* __restrict__ misc_arr,
                                                float* __restrict__ out) {
    const int tid = threadIdx.x;
    const float nld = nld_p[0];
    const float inv_sig = expf(-nld);
    const float nprec = inv_sig * inv_sig;

    double s1 = 0.0, s2 = 0.0;
    for (int b = tid; b < M_DIM; b += 256) {
        float c = Cnt[b];
        const float4* qp = (const float4*)(qpart + (size_t)b * NB_N);
        float q = 0.f;
        #pragma unroll
        for (int v4 = 0; v4 < 4; ++v4) {
            float4 qv = qp[v4];
            q += qv.x + qv.y + qv.z + qv.w;
        }
        float d = (Y[b] - U[b]) * inv_sig;
        float pl = -0.5f * d * d - nld - 0.5f * LOG2PI_F;
        float tt = 0.5f * q * c * c * nprec;
        s1 += (double)c;
        s2 += (double)((pl - tt) * c);
    }

    double wm2 = 0.0, tcd = 0.0, wls = 0.0, offs = 0.0;
    for (int i = tid; i < K_DIM; i += 256) {
        float w = Wm[i];
        wm2 += (double)w * (double)w;
        float ld = Wld[i];
        tcd += exp(2.0 * (double)ld);
        wls += (double)ld;
    }
    for (int i = tid; i < 1024; i += 256) offs += (double)misc_arr[i];

    __shared__ double red[6][4];
    double vals[6] = {s1, s2, wm2, tcd, wls, offs};
    #pragma unroll
    for (int s = 0; s < 6; ++s) {
        double v = vals[s];
        #pragma unroll
        for (int off = 32; off; off >>= 1) v += __shfl_down(v, off);
        if ((tid & 63) == 0) red[s][tid >> 6] = v;
    }
    __syncthreads();
    if (tid == 0) {
        double S1 = red[0][0] + red[0][1] + red[0][2] + red[0][3];
        double S2 = red[1][0] + red[1][1] + red[1][2] + red[1][3];
        double MSE = red[2][0] + red[2][1] + red[2][2] + red[2][3];
        double TCD = red[3][0] + red[3][1] + red[3][2] + red[3][3];
        double WLS = red[4][0] + red[4][1] + red[4][2] + red[4][3];
        double OFFS = red[5][0] + red[5][1] + red[5][2] + red[5][3];

        double trace_cov = OFFS + TCD;                     // sum(L*L)
        double kl = 0.5 * (MSE + trace_cov - 2.0 * WLS);   // prior_scale=1
        double wish = 1.5 * (-2.0 * (double)nld) - 0.005 * (double)nprec;
        double elbo = S2 / S1 + 1e-4 * (wish - kl);
        out[0] = (float)(-elbo);
    }
}

// ---------------------------------------------------------------------------
extern "C" void kernel_launch(void* const* d_in, const int* in_sizes, int n_in,
                              void* d_out, int out_size, void* d_ws, size_t ws_size,
                              hipStream_t stream) {
    const float* x    = (const float*)d_in[0];
    const float* y    = (const float*)d_in[1];
    const float* cnt  = (const float*)d_in[2];
    // d_in[3] = noise_mean (unused by the reference math)
    const float* nld  = (const float*)d_in[4];
    const float* Wm   = (const float*)d_in[5];
    const float* Wld  = (const float*)d_in[6];
    const float* Woff = (const float*)d_in[7];

    char* ws = (char*)d_ws;
    bf16_t* Xb     = (bf16_t*)(ws);                 // 16384*2048*2 = 67108864
    bf16_t* Lt     = (bf16_t*)(ws + 67108864);      // 2048*2048*2  =  8388608
    float*  U      = (float*)(ws + 75497472);       // 16384*4      =    65536
    float*  qpart  = (float*)(ws + 75563008);       // 16384*16*4   =  1048576
    float*  misc   = (float*)(ws + 76611584);       // 1024*4       =     4096

    build_Lt<<<dim3(32, 32), 256, 0, stream>>>(Woff, Wld, Lt, misc);
    prep_x<<<dim3(M_DIM), 256, 0, stream>>>(x, Wm, Xb, U);
    quad_gemm<<<dim3(NB_M, NB_N), 256, 0, stream>>>(Xb, Lt, qpart);
    finalize<<<1, 256, 0, stream>>>(y, cnt, nld, Wm, Wld, U, qpart, misc, (float*)d_out);
}